// Round 7
// baseline (1638.591 us; speedup 1.0000x reference)
//
#include <hip/hip_runtime.h>
#include <math.h>

#pragma clang fp contract(off)   // no implicit fusion; FMA only where ref has it

// Problem constants (fixed by the reference)
#define BB   8
#define NN   16384
#define FF   32
#define SS   2048
#define KK   32
#define OUTC 128

// ---------------------------------------------------------------------------
// Reference-bit-exact fp32 helpers (model validated by the R0-R5 absmax trail):
//
// x_sq / s_sq: numpy pairwise_sum scalar 8-accumulator block (n=32, no FMA):
//   r[j] = ((a[j]^2 + a[j+8]^2) + a[j+16]^2) + a[j+24]^2
//   res  = ((r0+r1) + (r2+r3)) + ((r4+r5) + (r6+r7))
__device__ __forceinline__ float np_sumsq32(const float* a) {
    float r[8];
#pragma unroll
    for (int j = 0; j < 8; j++) r[j] = a[j] * a[j];
#pragma unroll
    for (int t = 1; t < 4; t++) {
#pragma unroll
        for (int j = 0; j < 8; j++) {
            float e = a[8 * t + j] * a[8 * t + j];
            r[j] = r[j] + e;
        }
    }
    return ((r[0] + r[1]) + (r[2] + r[3])) + ((r[4] + r[5]) + (r[6] + r[7]));
}
// cross: BLAS sgemm micro-kernel order — single accumulator, k ascending,
// FUSED multiply-add per k (vector lanes span M/N, so per-element the k-chain
// is strictly sequential FMA). Evidence: only R0's fmaf chain matched ref at
// the dominant flip site; all no-FMA/tree orders missed it identically.
__device__ __forceinline__ float np_dot32(const float* a, const float* b) {
    float s = 0.f;
#pragma unroll
    for (int i = 0; i < 32; i++) s = fmaf(a[i], b[i], s);
    return s;
}

// ---------------------------------------------------------------------------
// K1a: x_sq[b,n] = ref-order sum_f x^2
__global__ __launch_bounds__(256) void xsq_kernel(const float* __restrict__ x,
                                                  float* __restrict__ xsq) {
    int gid = blockIdx.x * 256 + threadIdx.x;      // < B*N
    const float4* r = (const float4*)(x + (size_t)gid * FF);
    float a[32];
#pragma unroll
    for (int j = 0; j < 8; j++) {
        float4 v = r[j];
        a[4 * j] = v.x; a[4 * j + 1] = v.y; a[4 * j + 2] = v.z; a[4 * j + 3] = v.w;
    }
    xsq[gid] = np_sumsq32(a);
}

// ---------------------------------------------------------------------------
// K1b: gather sampled features (row-major [B,S,F]) + ref-order s_sq
__global__ __launch_bounds__(256) void gather_kernel(const float* __restrict__ x,
                                                     const int* __restrict__ sidx,
                                                     float* __restrict__ sampled,
                                                     float* __restrict__ ssq) {
    int gid = blockIdx.x * 256 + threadIdx.x;      // < B*S
    int b = gid >> 11;
    int idx = sidx[gid];
    const float4* r = (const float4*)(x + ((size_t)b * NN + idx) * FF);
    float4* wo = (float4*)(sampled + (size_t)gid * FF);
    float a[32];
#pragma unroll
    for (int j = 0; j < 8; j++) {
        float4 v = r[j];
        a[4 * j] = v.x; a[4 * j + 1] = v.y; a[4 * j + 2] = v.z; a[4 * j + 3] = v.w;
        wo[j] = v;
    }
    ssq[gid] = np_sumsq32(a);
}

// ---------------------------------------------------------------------------
// K1c: sampled [B,S,F] -> output sampled_batch [B,F,S] (transpose via LDS)
__global__ __launch_bounds__(256) void transpose_kernel(const float* __restrict__ sampled,
                                                        float* __restrict__ out_samp) {
    __shared__ float tile[32][65];
    int b = blockIdx.x >> 5, sg = blockIdx.x & 31;
    int s0 = sg * 64;
    int tid = threadIdx.x;
    int f = tid & 31, si = tid >> 5;               // si in 0..7
#pragma unroll
    for (int r = 0; r < 8; r++) {
        int s = r * 8 + si;
        tile[f][s] = sampled[((size_t)b * SS + s0 + s) * FF + f];
    }
    __syncthreads();
#pragma unroll
    for (int r = 0; r < 8; r++) {
        int flat = r * 256 + tid;
        int fo = flat >> 6, sw = flat & 63;
        out_samp[((size_t)b * FF + fo) * SS + s0 + sw] = tile[fo][sw];
    }
}

// ---------------------------------------------------------------------------
// K2: per-point MLP, h2[b,n,:] = W2 @ relu(W1 @ x + b1) + b2  (fp32, VALU)
// Continuous path: no bit-matching needed (error ~1e-6 << 0.09375 threshold).
__global__ __launch_bounds__(256) void mlp_kernel(const float* __restrict__ x,
                                                  const float* __restrict__ W1,
                                                  const float* __restrict__ b1,
                                                  const float* __restrict__ W2,
                                                  const float* __restrict__ b2,
                                                  float* __restrict__ h2) {
    __shared__ float xs[64][36];          // padded: b128 reads spread across banks
    __shared__ float hs[8512];            // h1t [128][65] then reused as h2s [64][133]
    int tid = threadIdx.x, lane = tid & 63;
    int wu = __builtin_amdgcn_readfirstlane(tid >> 6);   // force SGPR (scalar loads)
    size_t p0 = (size_t)blockIdx.x * 64;

    for (int i = tid; i < 64 * 8; i += 256) {
        int row = i >> 3, seg = i & 7;
        *(float4*)&xs[row][seg * 4] = *(const float4*)(x + (p0 + row) * FF + seg * 4);
    }
    __syncthreads();

    float xr[32];
    {
        const float4* r = (const float4*)&xs[lane][0];
#pragma unroll
        for (int j = 0; j < 8; j++) {
            float4 v = r[j];
            xr[4 * j] = v.x; xr[4 * j + 1] = v.y; xr[4 * j + 2] = v.z; xr[4 * j + 3] = v.w;
        }
    }
    // layer 1: h1t[o][p], pad 65 -> bank (o+p)%32, conflict-free-ish
#pragma unroll 4
    for (int i = 0; i < 32; i++) {
        int o = wu * 32 + i;
        const float4* wr = (const float4*)(W1 + o * FF);
        float a = b1[o];
#pragma unroll
        for (int j = 0; j < 8; j++) {
            float4 v = wr[j];
            a = fmaf(v.x, xr[4 * j], a);     a = fmaf(v.y, xr[4 * j + 1], a);
            a = fmaf(v.z, xr[4 * j + 2], a); a = fmaf(v.w, xr[4 * j + 3], a);
        }
        hs[o * 65 + lane] = fmaxf(a, 0.f);
    }
    __syncthreads();
    // layer 2
    float acc[32];
#pragma unroll
    for (int i = 0; i < 32; i++) acc[i] = b2[wu * 32 + i];
    for (int k4 = 0; k4 < 32; k4++) {
        float h0 = hs[(4 * k4 + 0) * 65 + lane];
        float h1v = hs[(4 * k4 + 1) * 65 + lane];
        float h2v = hs[(4 * k4 + 2) * 65 + lane];
        float h3v = hs[(4 * k4 + 3) * 65 + lane];
#pragma unroll
        for (int i = 0; i < 32; i++) {
            const float4 v = *(const float4*)(W2 + (wu * 32 + i) * OUTC + 4 * k4); // scalar loads
            acc[i] = fmaf(v.x, h0, acc[i]);  acc[i] = fmaf(v.y, h1v, acc[i]);
            acc[i] = fmaf(v.z, h2v, acc[i]); acc[i] = fmaf(v.w, h3v, acc[i]);
        }
    }
    __syncthreads();                       // everyone done reading h1t
    // stage h2 tile [p][o] pad 133 -> bank (5p+o)%32
#pragma unroll 4
    for (int i = 0; i < 32; i++) hs[lane * 133 + wu * 32 + i] = acc[i];
    __syncthreads();
    // coalesced global write
    for (int j = 0; j < 32; j++) {
        int flat = j * 256 + tid;
        int p = flat >> 7, o = flat & 127;
        h2[(p0 + p) * OUTC + o] = hs[p * 133 + o];
    }
}

// ---------------------------------------------------------------------------
// K3: ref-bit-exact fp32 distance + stable top-32 (KEEP=32, strict d<tau,
// lex (d,idx) sort == stable top_k when d matches ref bitwise).
#define KEEP 32

__device__ __forceinline__ bool lessp(float da, int ia, float db, int ib) {
    return da < db || (da == db && ia < ib);
}
__device__ __forceinline__ void cswap(float& d, int& i, int j, bool dirAsc, int lane) {
    float od = __shfl_xor(d, j);
    int   oi = __shfl_xor(i, j);
    bool lower = (lane & j) == 0;
    bool oLess = lessp(od, oi, d, i);
    if (oLess == (lower == dirAsc)) { d = od; i = oi; }
}
__device__ __forceinline__ void sort64(float& d, int& i, bool asc, int lane) {
#pragma unroll
    for (int k = 2; k <= 64; k <<= 1) {
        bool ba = (((lane & k) == 0) == asc);
#pragma unroll
        for (int j = k >> 1; j > 0; j >>= 1) cswap(d, i, j, ba, lane);
    }
}
// sort all valid slots, keep lowest-64 lex-sorted in slots [0,64);
// cnt <- KEEP, tau <- 32nd-smallest (strict).
__device__ __forceinline__ void wave_compact(int qq, int lane,
                                             float (*bufd)[128], int (*bufi)[128],
                                             int* cnt, float* tau) {
    int m = cnt[qq];
    float d0 = (lane < m) ? bufd[qq][lane] : INFINITY;
    int   i0 = (lane < m) ? bufi[qq][lane] : 0x7fffffff;
    float d1 = (lane + 64 < m) ? bufd[qq][lane + 64] : INFINITY;
    int   i1 = (lane + 64 < m) ? bufi[qq][lane + 64] : 0x7fffffff;
    sort64(d0, i0, true, lane);            // first 64 ascending
    sort64(d1, i1, false, lane);           // second 64 descending
    bool t = lessp(d1, i1, d0, i0);        // bitonic-merge first step (keep mins)
    float ld = t ? d1 : d0;
    int   li = t ? i1 : i0;
#pragma unroll
    for (int j = 32; j > 0; j >>= 1) cswap(ld, li, j, true, lane);  // cleanup
    bufd[qq][lane] = ld; bufi[qq][lane] = li;   // sorted lowest-64
    float t32 = __shfl(ld, 31);            // 32nd-smallest so far
    if (lane == 0) { cnt[qq] = KEEP; tau[qq] = t32; }
}

__global__ __launch_bounds__(256, 2) void topk_kernel(const float* __restrict__ x,
                                                      const float* __restrict__ x_sq,
                                                      const float* __restrict__ sampled,
                                                      const float* __restrict__ s_sq,
                                                      int* __restrict__ nbr) {
    int b = blockIdx.x & 7;                 // XCD-by-batch swizzle: batch b on XCD b
    int qg = blockIdx.x >> 3;               // 0..127
    int tid = threadIdx.x, lane = tid & 63, w = tid >> 6;
    __shared__ float xs[64][36];
    __shared__ float xsqs[64];
    __shared__ float bufd[16][128];
    __shared__ int   bufi[16][128];
    __shared__ int   cnt[16];
    __shared__ float tau[16];
    int s0 = qg * 16;
    const float* xb = x + (size_t)b * (NN * FF);
    if (tid < 16) { cnt[tid] = 0; tau[tid] = INFINITY; }

    // query features replicated in VGPRs (constant over the whole scan)
    float sa[4][32];
    float ssq[4];
#pragma unroll
    for (int q = 0; q < 4; q++) {
        const float4* sp = (const float4*)(sampled + ((size_t)b * SS + s0 + w * 4 + q) * FF);
#pragma unroll
        for (int j = 0; j < 8; j++) {
            float4 v = sp[j];
            sa[q][4 * j] = v.x; sa[q][4 * j + 1] = v.y;
            sa[q][4 * j + 2] = v.z; sa[q][4 * j + 3] = v.w;
        }
        ssq[q] = s_sq[b * SS + s0 + w * 4 + q];
    }
    __syncthreads();

    for (int t = 0; t < NN / 64; t++) {
        int n0 = t * 64;
        __syncthreads();
        for (int i = tid; i < 512; i += 256) {
            int row = i >> 3, seg = i & 7;
            *(float4*)&xs[row][seg * 4] = *(const float4*)(xb + (size_t)(n0 + row) * FF + (seg << 2));
        }
        if (tid < 64) xsqs[tid] = x_sq[b * NN + n0 + tid];
        __syncthreads();

        float xa[32];
        {
            const float4* rr = (const float4*)&xs[lane][0];
#pragma unroll
            for (int j = 0; j < 8; j++) {
                float4 v = rr[j];
                xa[4 * j] = v.x; xa[4 * j + 1] = v.y; xa[4 * j + 2] = v.z; xa[4 * j + 3] = v.w;
            }
        }
        float xq = xsqs[lane];
        int n = n0 + lane;
#pragma unroll
        for (int q = 0; q < 4; q++) {
            int qq = w * 4 + q;
            float c = np_dot32(sa[q], xa);        // BLAS-order sequential FMA chain
            float t1 = ssq[q] + xq;               // fl(s_sq + x_sq)
            float c2 = c + c;                     // 2.0*cross (exact)
            float d = t1 - c2;                    // fl(t1 - c2)
            float tq = tau[qq];
            bool pred = d < tq;                   // strict: ties after tau excluded (stable)
            unsigned long long mask = __ballot(pred);
            if (mask) {
                int tot = __builtin_popcountll(mask);
                int leader = __builtin_ctzll(mask);
                int base = 0;
                if (lane == leader) base = atomicAdd(&cnt[qq], tot);
                base = __shfl(base, leader);
                if (pred) {
                    int pos = base + __builtin_popcountll(mask & ((1ull << lane) - 1ull));
                    bufd[qq][pos] = d;            // max pos 127: cnt<=64 at tile start
                    bufi[qq][pos] = n;
                }
            }
        }
#pragma unroll
        for (int q = 0; q < 4; q++) {
            int qq = w * 4 + q;
            if (cnt[qq] > 64) wave_compact(qq, lane, bufd, bufi, cnt, tau);
        }
    }
    // final: compact (lex-sorts survivors) and emit first 32 per query
#pragma unroll
    for (int q = 0; q < 4; q++) {
        int qq = w * 4 + q;
        wave_compact(qq, lane, bufd, bufi, cnt, tau);
        int s = s0 + qq;
        if (lane < 32) nbr[((size_t)b * SS + s) * KK + lane] = bufi[qq][lane];
    }
}

// ---------------------------------------------------------------------------
// K4: features_batch[b,o,s] = max_k h2[b, nbr[b,s,k], o]; block=128, 16 s/block
__global__ __launch_bounds__(128) void maxgather_kernel(const float* __restrict__ h2,
                                                        const int* __restrict__ nbr,
                                                        float* __restrict__ out_feat) {
    __shared__ float fs[128][17];
    int b = blockIdx.x & 7;                 // batch-per-XCD swizzle for h2 L2 locality
    int sg = blockIdx.x >> 3;               // 0..127
    int s0 = sg * 16;
    int tid = threadIdx.x;                  // o = tid (0..127)
    for (int si = 0; si < 16; si++) {
        int s = s0 + si;
        const int* row = nbr + ((size_t)b * SS + s) * KK;
        float m = -INFINITY;
#pragma unroll 4
        for (int k = 0; k < KK; k++) {
            int idx = row[k];               // uniform -> scalar load
            float v = h2[((size_t)b * NN + idx) * OUTC + tid];  // 512B coalesced
            m = fmaxf(m, v);
        }
        fs[tid][si] = m;
    }
    __syncthreads();
#pragma unroll
    for (int j = 0; j < 16; j++) {
        int flat = j * 128 + tid;
        int fo = flat >> 4, sw = flat & 15;
        out_feat[((size_t)b * OUTC + fo) * SS + s0 + sw] = fs[fo][sw];
    }
}

// ---------------------------------------------------------------------------
extern "C" void kernel_launch(void* const* d_in, const int* in_sizes, int n_in,
                              void* d_out, int out_size, void* d_ws, size_t ws_size,
                              hipStream_t stream) {
    const float* x    = (const float*)d_in[0];
    const int*   sidx = (const int*)d_in[1];
    const float* W1   = (const float*)d_in[2];
    const float* b1   = (const float*)d_in[3];
    const float* W2   = (const float*)d_in[4];
    const float* b2   = (const float*)d_in[5];

    float* out_feat = (float*)d_out;                       // [B,128,S]
    float* out_samp = out_feat + (size_t)BB * OUTC * SS;   // [B,32,S]

    // workspace carve-up (~70 MB)
    float* h2      = (float*)d_ws;                         // B*N*128 fp32 = 64 MB
    float* sampled = h2 + (size_t)BB * NN * OUTC;          // B*S*F
    float* xsq     = sampled + (size_t)BB * SS * FF;       // B*N
    float* ssq     = xsq + (size_t)BB * NN;                // B*S
    int*   nbr     = (int*)(ssq + (size_t)BB * SS);        // B*S*K

    xsq_kernel<<<dim3(BB * NN / 256), dim3(256), 0, stream>>>(x, xsq);
    gather_kernel<<<dim3(BB * SS / 256), dim3(256), 0, stream>>>(x, sidx, sampled, ssq);
    mlp_kernel<<<dim3(BB * NN / 64), dim3(256), 0, stream>>>(x, W1, b1, W2, b2, h2);
    transpose_kernel<<<dim3(BB * SS / 64), dim3(256), 0, stream>>>(sampled, out_samp);
    topk_kernel<<<dim3(BB * SS / 16), dim3(256), 0, stream>>>(x, xsq, sampled, ssq, nbr);
    maxgather_kernel<<<dim3(BB * SS / 16), dim3(128), 0, stream>>>(h2, nbr, out_feat);
}

// Round 8
// 1198.372 us; speedup vs baseline: 1.3673x; 1.3673x over previous
//
#include <hip/hip_runtime.h>
#include <math.h>

#pragma clang fp contract(off)   // no implicit fusion; FMA only where ref has it

// Problem constants (fixed by the reference)
#define BB   8
#define NN   16384
#define FF   32
#define SS   2048
#define KK   32
#define OUTC 128

// ---------------------------------------------------------------------------
// Reference-bit-exact fp32 helpers (validated R0-R7):
// x_sq / s_sq: numpy pairwise_sum scalar 8-accumulator block (n=32, no FMA)
__device__ __forceinline__ float np_sumsq32(const float* a) {
    float r[8];
#pragma unroll
    for (int j = 0; j < 8; j++) r[j] = a[j] * a[j];
#pragma unroll
    for (int t = 1; t < 4; t++) {
#pragma unroll
        for (int j = 0; j < 8; j++) {
            float e = a[8 * t + j] * a[8 * t + j];
            r[j] = r[j] + e;
        }
    }
    return ((r[0] + r[1]) + (r[2] + r[3])) + ((r[4] + r[5]) + (r[6] + r[7]));
}

// ---------------------------------------------------------------------------
// K1a: x_sq[b,n] = ref-order sum_f x^2
__global__ __launch_bounds__(256) void xsq_kernel(const float* __restrict__ x,
                                                  float* __restrict__ xsq) {
    int gid = blockIdx.x * 256 + threadIdx.x;      // < B*N
    const float4* r = (const float4*)(x + (size_t)gid * FF);
    float a[32];
#pragma unroll
    for (int j = 0; j < 8; j++) {
        float4 v = r[j];
        a[4 * j] = v.x; a[4 * j + 1] = v.y; a[4 * j + 2] = v.z; a[4 * j + 3] = v.w;
    }
    xsq[gid] = np_sumsq32(a);
}

// ---------------------------------------------------------------------------
// K1b: gather sampled features (row-major [B,S,F]) + ref-order s_sq
__global__ __launch_bounds__(256) void gather_kernel(const float* __restrict__ x,
                                                     const int* __restrict__ sidx,
                                                     float* __restrict__ sampled,
                                                     float* __restrict__ ssq) {
    int gid = blockIdx.x * 256 + threadIdx.x;      // < B*S
    int b = gid >> 11;
    int idx = sidx[gid];
    const float4* r = (const float4*)(x + ((size_t)b * NN + idx) * FF);
    float4* wo = (float4*)(sampled + (size_t)gid * FF);
    float a[32];
#pragma unroll
    for (int j = 0; j < 8; j++) {
        float4 v = r[j];
        a[4 * j] = v.x; a[4 * j + 1] = v.y; a[4 * j + 2] = v.z; a[4 * j + 3] = v.w;
        wo[j] = v;
    }
    ssq[gid] = np_sumsq32(a);
}

// ---------------------------------------------------------------------------
// K1c: sampled [B,S,F] -> output sampled_batch [B,F,S] (transpose via LDS)
__global__ __launch_bounds__(256) void transpose_kernel(const float* __restrict__ sampled,
                                                        float* __restrict__ out_samp) {
    __shared__ float tile[32][65];
    int b = blockIdx.x >> 5, sg = blockIdx.x & 31;
    int s0 = sg * 64;
    int tid = threadIdx.x;
    int f = tid & 31, si = tid >> 5;               // si in 0..7
#pragma unroll
    for (int r = 0; r < 8; r++) {
        int s = r * 8 + si;
        tile[f][s] = sampled[((size_t)b * SS + s0 + s) * FF + f];
    }
    __syncthreads();
#pragma unroll
    for (int r = 0; r < 8; r++) {
        int flat = r * 256 + tid;
        int fo = flat >> 6, sw = flat & 63;
        out_samp[((size_t)b * FF + fo) * SS + s0 + sw] = tile[fo][sw];
    }
}

// ---------------------------------------------------------------------------
// K2: per-point MLP, h2[b,n,:] = W2 @ relu(W1 @ x + b1) + b2  (fp32, VALU)
__global__ __launch_bounds__(256) void mlp_kernel(const float* __restrict__ x,
                                                  const float* __restrict__ W1,
                                                  const float* __restrict__ b1,
                                                  const float* __restrict__ W2,
                                                  const float* __restrict__ b2,
                                                  float* __restrict__ h2) {
    __shared__ float xs[64][36];          // padded
    __shared__ float hs[8512];            // h1t [128][65] then reused as h2s [64][133]
    int tid = threadIdx.x, lane = tid & 63;
    int wu = __builtin_amdgcn_readfirstlane(tid >> 6);
    size_t p0 = (size_t)blockIdx.x * 64;

    for (int i = tid; i < 64 * 8; i += 256) {
        int row = i >> 3, seg = i & 7;
        *(float4*)&xs[row][seg * 4] = *(const float4*)(x + (p0 + row) * FF + seg * 4);
    }
    __syncthreads();

    float xr[32];
    {
        const float4* r = (const float4*)&xs[lane][0];
#pragma unroll
        for (int j = 0; j < 8; j++) {
            float4 v = r[j];
            xr[4 * j] = v.x; xr[4 * j + 1] = v.y; xr[4 * j + 2] = v.z; xr[4 * j + 3] = v.w;
        }
    }
#pragma unroll 4
    for (int i = 0; i < 32; i++) {
        int o = wu * 32 + i;
        const float4* wr = (const float4*)(W1 + o * FF);
        float a = b1[o];
#pragma unroll
        for (int j = 0; j < 8; j++) {
            float4 v = wr[j];
            a = fmaf(v.x, xr[4 * j], a);     a = fmaf(v.y, xr[4 * j + 1], a);
            a = fmaf(v.z, xr[4 * j + 2], a); a = fmaf(v.w, xr[4 * j + 3], a);
        }
        hs[o * 65 + lane] = fmaxf(a, 0.f);
    }
    __syncthreads();
    float acc[32];
#pragma unroll
    for (int i = 0; i < 32; i++) acc[i] = b2[wu * 32 + i];
    for (int k4 = 0; k4 < 32; k4++) {
        float h0 = hs[(4 * k4 + 0) * 65 + lane];
        float h1v = hs[(4 * k4 + 1) * 65 + lane];
        float h2v = hs[(4 * k4 + 2) * 65 + lane];
        float h3v = hs[(4 * k4 + 3) * 65 + lane];
#pragma unroll
        for (int i = 0; i < 32; i++) {
            const float4 v = *(const float4*)(W2 + (wu * 32 + i) * OUTC + 4 * k4);
            acc[i] = fmaf(v.x, h0, acc[i]);  acc[i] = fmaf(v.y, h1v, acc[i]);
            acc[i] = fmaf(v.z, h2v, acc[i]); acc[i] = fmaf(v.w, h3v, acc[i]);
        }
    }
    __syncthreads();
#pragma unroll 4
    for (int i = 0; i < 32; i++) hs[lane * 133 + wu * 32 + i] = acc[i];
    __syncthreads();
    for (int j = 0; j < 32; j++) {
        int flat = j * 256 + tid;
        int p = flat >> 7, o = flat & 127;
        h2[(p0 + p) * OUTC + o] = hs[p * 133 + o];
    }
}

// ---------------------------------------------------------------------------
// K3 v2: 2 queries/wave (sa fits VGPRs — R7 spilled sa[4][32] to scratch,
// VGPR_Count=104 < 128 needed, VALUBusy 28%). cnt/tau in uniform registers.
__device__ __forceinline__ bool lessp(float da, int ia, float db, int ib) {
    return da < db || (da == db && ia < ib);
}
__device__ __forceinline__ void cswap(float& d, int& i, int j, bool dirAsc, int lane) {
    float od = __shfl_xor(d, j);
    int   oi = __shfl_xor(i, j);
    bool lower = (lane & j) == 0;
    bool oLess = lessp(od, oi, d, i);
    if (oLess == (lower == dirAsc)) { d = od; i = oi; }
}
__device__ __forceinline__ void sort64(float& d, int& i, bool asc, int lane) {
#pragma unroll
    for (int k = 2; k <= 64; k <<= 1) {
        bool ba = (((lane & k) == 0) == asc);
#pragma unroll
        for (int j = k >> 1; j > 0; j >>= 1) cswap(d, i, j, ba, lane);
    }
}
// sort m valid slots, keep lowest-64 lex-sorted in [0,64); return 32nd-smallest
__device__ __forceinline__ float wave_compact2(float* bd, int* bi, int m, int lane) {
    float d0 = (lane < m) ? bd[lane] : INFINITY;
    int   i0 = (lane < m) ? bi[lane] : 0x7fffffff;
    float d1 = (lane + 64 < m) ? bd[lane + 64] : INFINITY;
    int   i1 = (lane + 64 < m) ? bi[lane + 64] : 0x7fffffff;
    sort64(d0, i0, true, lane);
    sort64(d1, i1, false, lane);
    bool t = lessp(d1, i1, d0, i0);
    float ld = t ? d1 : d0;
    int   li = t ? i1 : i0;
#pragma unroll
    for (int j = 32; j > 0; j >>= 1) cswap(ld, li, j, true, lane);
    bd[lane] = ld; bi[lane] = li;
    return __shfl(ld, 31);                 // uniform across wave
}

__global__ __launch_bounds__(256, 4) void topk_kernel(const float* __restrict__ x,
                                                      const float* __restrict__ x_sq,
                                                      const float* __restrict__ sampled,
                                                      const float* __restrict__ s_sq,
                                                      int* __restrict__ nbr) {
    int b = blockIdx.x & 7;                 // XCD-by-batch swizzle
    int qg = blockIdx.x >> 3;               // 0..255
    int tid = threadIdx.x, lane = tid & 63, w = tid >> 6;
    __shared__ float xs[64][36];
    __shared__ float bufd[8][128];
    __shared__ int   bufi[8][128];
    int s0 = qg * 8;                        // 8 queries per block, 2 per wave
    const float* xb = x + (size_t)b * (NN * FF);
    const float* xqb = x_sq + (size_t)b * NN;

    // 2 query feature vectors in VGPRs (64 regs) — constant over the scan
    float sa[2][32];
    float ssq[2];
#pragma unroll
    for (int q = 0; q < 2; q++) {
        const float4* sp = (const float4*)(sampled + ((size_t)b * SS + s0 + w * 2 + q) * FF);
#pragma unroll
        for (int j = 0; j < 8; j++) {
            float4 v = sp[j];
            sa[q][4 * j] = v.x; sa[q][4 * j + 1] = v.y;
            sa[q][4 * j + 2] = v.z; sa[q][4 * j + 3] = v.w;
        }
        ssq[q] = s_sq[b * SS + s0 + w * 2 + q];
    }
    float* bq0d = &bufd[w * 2 + 0][0];  int* bq0i = &bufi[w * 2 + 0][0];
    float* bq1d = &bufd[w * 2 + 1][0];  int* bq1i = &bufi[w * 2 + 1][0];
    int   cnt0 = 0, cnt1 = 0;              // wave-uniform
    float tau0 = INFINITY, tau1 = INFINITY;

    for (int t = 0; t < NN / 64; t++) {
        int n0 = t * 64;
        __syncthreads();
        for (int i = tid; i < 512; i += 256) {
            int row = i >> 3, seg = i & 7;
            *(float4*)&xs[row][seg * 4] = *(const float4*)(xb + (size_t)(n0 + row) * FF + (seg << 2));
        }
        __syncthreads();

        int n = n0 + lane;
        float xq = xqb[n];                  // coalesced, L2-hot
        // both dot chains interleaved (independent -> hides FMA dep latency);
        // each chain is the ref-exact sequential FMA order.
        float c0 = 0.f, c1 = 0.f;
        {
            const float4* rr = (const float4*)&xs[lane][0];
#pragma unroll
            for (int j = 0; j < 8; j++) {
                float4 v = rr[j];
                c0 = fmaf(sa[0][4 * j], v.x, c0);     c1 = fmaf(sa[1][4 * j], v.x, c1);
                c0 = fmaf(sa[0][4 * j + 1], v.y, c0); c1 = fmaf(sa[1][4 * j + 1], v.y, c1);
                c0 = fmaf(sa[0][4 * j + 2], v.z, c0); c1 = fmaf(sa[1][4 * j + 2], v.z, c1);
                c0 = fmaf(sa[0][4 * j + 3], v.w, c0); c1 = fmaf(sa[1][4 * j + 3], v.w, c1);
            }
        }
        float d0v = (ssq[0] + xq) - (c0 + c0);   // ref combine order
        float d1v = (ssq[1] + xq) - (c1 + c1);

        unsigned long long m0 = __ballot(d0v < tau0);
        if (m0) {
            int pos = cnt0 + __builtin_popcountll(m0 & ((1ull << lane) - 1ull));
            if (d0v < tau0) { bq0d[pos] = d0v; bq0i[pos] = n; }
            cnt0 += __builtin_popcountll(m0);
            if (cnt0 > 64) { tau0 = wave_compact2(bq0d, bq0i, cnt0, lane); cnt0 = 32; }
        }
        unsigned long long m1 = __ballot(d1v < tau1);
        if (m1) {
            int pos = cnt1 + __builtin_popcountll(m1 & ((1ull << lane) - 1ull));
            if (d1v < tau1) { bq1d[pos] = d1v; bq1i[pos] = n; }
            cnt1 += __builtin_popcountll(m1);
            if (cnt1 > 64) { tau1 = wave_compact2(bq1d, bq1i, cnt1, lane); cnt1 = 32; }
        }
    }
    // final: compact (lex-sorts survivors) and emit first 32 per query
    wave_compact2(bq0d, bq0i, cnt0, lane);
    wave_compact2(bq1d, bq1i, cnt1, lane);
    int s = s0 + w * 2;
    if (lane < 32) {
        nbr[((size_t)b * SS + s) * KK + lane] = bq0i[lane];
        nbr[((size_t)b * SS + s + 1) * KK + lane] = bq1i[lane];
    }
}

// ---------------------------------------------------------------------------
// K4: features_batch[b,o,s] = max_k h2[b, nbr[b,s,k], o]; block=128, 16 s/block
__global__ __launch_bounds__(128) void maxgather_kernel(const float* __restrict__ h2,
                                                        const int* __restrict__ nbr,
                                                        float* __restrict__ out_feat) {
    __shared__ float fs[128][17];
    int b = blockIdx.x & 7;
    int sg = blockIdx.x >> 3;               // 0..127
    int s0 = sg * 16;
    int tid = threadIdx.x;                  // o = tid (0..127)
    for (int si = 0; si < 16; si++) {
        int s = s0 + si;
        const int* row = nbr + ((size_t)b * SS + s) * KK;
        float m = -INFINITY;
#pragma unroll 4
        for (int k = 0; k < KK; k++) {
            int idx = row[k];
            float v = h2[((size_t)b * NN + idx) * OUTC + tid];
            m = fmaxf(m, v);
        }
        fs[tid][si] = m;
    }
    __syncthreads();
#pragma unroll
    for (int j = 0; j < 16; j++) {
        int flat = j * 128 + tid;
        int fo = flat >> 4, sw = flat & 15;
        out_feat[((size_t)b * OUTC + fo) * SS + s0 + sw] = fs[fo][sw];
    }
}

// ---------------------------------------------------------------------------
extern "C" void kernel_launch(void* const* d_in, const int* in_sizes, int n_in,
                              void* d_out, int out_size, void* d_ws, size_t ws_size,
                              hipStream_t stream) {
    const float* x    = (const float*)d_in[0];
    const int*   sidx = (const int*)d_in[1];
    const float* W1   = (const float*)d_in[2];
    const float* b1   = (const float*)d_in[3];
    const float* W2   = (const float*)d_in[4];
    const float* b2   = (const float*)d_in[5];

    float* out_feat = (float*)d_out;                       // [B,128,S]
    float* out_samp = out_feat + (size_t)BB * OUTC * SS;   // [B,32,S]

    float* h2      = (float*)d_ws;                         // B*N*128 fp32 = 64 MB
    float* sampled = h2 + (size_t)BB * NN * OUTC;          // B*S*F
    float* xsq     = sampled + (size_t)BB * SS * FF;       // B*N
    float* ssq     = xsq + (size_t)BB * NN;                // B*S
    int*   nbr     = (int*)(ssq + (size_t)BB * SS);        // B*S*K

    xsq_kernel<<<dim3(BB * NN / 256), dim3(256), 0, stream>>>(x, xsq);
    gather_kernel<<<dim3(BB * SS / 256), dim3(256), 0, stream>>>(x, sidx, sampled, ssq);
    mlp_kernel<<<dim3(BB * NN / 64), dim3(256), 0, stream>>>(x, W1, b1, W2, b2, h2);
    transpose_kernel<<<dim3(BB * SS / 64), dim3(256), 0, stream>>>(sampled, out_samp);
    topk_kernel<<<dim3(BB * SS / 8), dim3(256), 0, stream>>>(x, xsq, sampled, ssq, nbr);
    maxgather_kernel<<<dim3(BB * SS / 16), dim3(128), 0, stream>>>(h2, nbr, out_feat);
}

// Round 9
// 1129.295 us; speedup vs baseline: 1.4510x; 1.0612x over previous
//
#include <hip/hip_runtime.h>
#include <math.h>

#pragma clang fp contract(off)   // no implicit fusion; FMA only where ref has it

// Problem constants (fixed by the reference)
#define BB   8
#define NN   16384
#define FF   32
#define SS   2048
#define KK   32
#define OUTC 128

// force a value into uniform (SGPR) representation
__device__ __forceinline__ float uni(float v) {
    return __uint_as_float(__builtin_amdgcn_readfirstlane(__float_as_uint(v)));
}

// ---------------------------------------------------------------------------
// Reference-bit-exact fp32 helpers (validated R0-R7):
// x_sq / s_sq: numpy pairwise_sum scalar 8-accumulator block (n=32, no FMA)
__device__ __forceinline__ float np_sumsq32(const float* a) {
    float r[8];
#pragma unroll
    for (int j = 0; j < 8; j++) r[j] = a[j] * a[j];
#pragma unroll
    for (int t = 1; t < 4; t++) {
#pragma unroll
        for (int j = 0; j < 8; j++) {
            float e = a[8 * t + j] * a[8 * t + j];
            r[j] = r[j] + e;
        }
    }
    return ((r[0] + r[1]) + (r[2] + r[3])) + ((r[4] + r[5]) + (r[6] + r[7]));
}

// ---------------------------------------------------------------------------
// K1a: x_sq[b,n] = ref-order sum_f x^2
__global__ __launch_bounds__(256) void xsq_kernel(const float* __restrict__ x,
                                                  float* __restrict__ xsq) {
    int gid = blockIdx.x * 256 + threadIdx.x;      // < B*N
    const float4* r = (const float4*)(x + (size_t)gid * FF);
    float a[32];
#pragma unroll
    for (int j = 0; j < 8; j++) {
        float4 v = r[j];
        a[4 * j] = v.x; a[4 * j + 1] = v.y; a[4 * j + 2] = v.z; a[4 * j + 3] = v.w;
    }
    xsq[gid] = np_sumsq32(a);
}

// ---------------------------------------------------------------------------
// K1b: gather sampled features (row-major [B,S,F]) + ref-order s_sq
__global__ __launch_bounds__(256) void gather_kernel(const float* __restrict__ x,
                                                     const int* __restrict__ sidx,
                                                     float* __restrict__ sampled,
                                                     float* __restrict__ ssq) {
    int gid = blockIdx.x * 256 + threadIdx.x;      // < B*S
    int b = gid >> 11;
    int idx = sidx[gid];
    const float4* r = (const float4*)(x + ((size_t)b * NN + idx) * FF);
    float4* wo = (float4*)(sampled + (size_t)gid * FF);
    float a[32];
#pragma unroll
    for (int j = 0; j < 8; j++) {
        float4 v = r[j];
        a[4 * j] = v.x; a[4 * j + 1] = v.y; a[4 * j + 2] = v.z; a[4 * j + 3] = v.w;
        wo[j] = v;
    }
    ssq[gid] = np_sumsq32(a);
}

// ---------------------------------------------------------------------------
// K1c: sampled [B,S,F] -> output sampled_batch [B,F,S] (transpose via LDS)
__global__ __launch_bounds__(256) void transpose_kernel(const float* __restrict__ sampled,
                                                        float* __restrict__ out_samp) {
    __shared__ float tile[32][65];
    int b = blockIdx.x >> 5, sg = blockIdx.x & 31;
    int s0 = sg * 64;
    int tid = threadIdx.x;
    int f = tid & 31, si = tid >> 5;               // si in 0..7
#pragma unroll
    for (int r = 0; r < 8; r++) {
        int s = r * 8 + si;
        tile[f][s] = sampled[((size_t)b * SS + s0 + s) * FF + f];
    }
    __syncthreads();
#pragma unroll
    for (int r = 0; r < 8; r++) {
        int flat = r * 256 + tid;
        int fo = flat >> 6, sw = flat & 63;
        out_samp[((size_t)b * FF + fo) * SS + s0 + sw] = tile[fo][sw];
    }
}

// ---------------------------------------------------------------------------
// K2: per-point MLP, h2[b,n,:] = W2 @ relu(W1 @ x + b1) + b2  (fp32, VALU)
__global__ __launch_bounds__(256) void mlp_kernel(const float* __restrict__ x,
                                                  const float* __restrict__ W1,
                                                  const float* __restrict__ b1,
                                                  const float* __restrict__ W2,
                                                  const float* __restrict__ b2,
                                                  float* __restrict__ h2) {
    __shared__ float xs[64][36];          // padded
    __shared__ float hs[8512];            // h1t [128][65] then reused as h2s [64][133]
    int tid = threadIdx.x, lane = tid & 63;
    int wu = __builtin_amdgcn_readfirstlane(tid >> 6);
    size_t p0 = (size_t)blockIdx.x * 64;

    for (int i = tid; i < 64 * 8; i += 256) {
        int row = i >> 3, seg = i & 7;
        *(float4*)&xs[row][seg * 4] = *(const float4*)(x + (p0 + row) * FF + seg * 4);
    }
    __syncthreads();

    float xr[32];
    {
        const float4* r = (const float4*)&xs[lane][0];
#pragma unroll
        for (int j = 0; j < 8; j++) {
            float4 v = r[j];
            xr[4 * j] = v.x; xr[4 * j + 1] = v.y; xr[4 * j + 2] = v.z; xr[4 * j + 3] = v.w;
        }
    }
#pragma unroll 4
    for (int i = 0; i < 32; i++) {
        int o = wu * 32 + i;
        const float4* wr = (const float4*)(W1 + o * FF);
        float a = b1[o];
#pragma unroll
        for (int j = 0; j < 8; j++) {
            float4 v = wr[j];
            a = fmaf(v.x, xr[4 * j], a);     a = fmaf(v.y, xr[4 * j + 1], a);
            a = fmaf(v.z, xr[4 * j + 2], a); a = fmaf(v.w, xr[4 * j + 3], a);
        }
        hs[o * 65 + lane] = fmaxf(a, 0.f);
    }
    __syncthreads();
    float acc[32];
#pragma unroll
    for (int i = 0; i < 32; i++) acc[i] = b2[wu * 32 + i];
    for (int k4 = 0; k4 < 32; k4++) {
        float h0 = hs[(4 * k4 + 0) * 65 + lane];
        float h1v = hs[(4 * k4 + 1) * 65 + lane];
        float h2v = hs[(4 * k4 + 2) * 65 + lane];
        float h3v = hs[(4 * k4 + 3) * 65 + lane];
#pragma unroll
        for (int i = 0; i < 32; i++) {
            const float4 v = *(const float4*)(W2 + (wu * 32 + i) * OUTC + 4 * k4);
            acc[i] = fmaf(v.x, h0, acc[i]);  acc[i] = fmaf(v.y, h1v, acc[i]);
            acc[i] = fmaf(v.z, h2v, acc[i]); acc[i] = fmaf(v.w, h3v, acc[i]);
        }
    }
    __syncthreads();
#pragma unroll 4
    for (int i = 0; i < 32; i++) hs[lane * 133 + wu * 32 + i] = acc[i];
    __syncthreads();
    for (int j = 0; j < 32; j++) {
        int flat = j * 256 + tid;
        int p = flat >> 7, o = flat & 127;
        h2[(p0 + p) * OUTC + o] = hs[p * 133 + o];
    }
}

// ---------------------------------------------------------------------------
// K3 v3: query features in SGPRs (wave-uniform; v_fma takes one SGPR operand).
// Kills the VGPR spill that capped R7 (VGPR 104) and R8 (VGPR 64, 12 MB
// scratch writes). K-loop VGPR footprint ~30.
__device__ __forceinline__ bool lessp(float da, int ia, float db, int ib) {
    return da < db || (da == db && ia < ib);
}
__device__ __forceinline__ void cswap(float& d, int& i, int j, bool dirAsc, int lane) {
    float od = __shfl_xor(d, j);
    int   oi = __shfl_xor(i, j);
    bool lower = (lane & j) == 0;
    bool oLess = lessp(od, oi, d, i);
    if (oLess == (lower == dirAsc)) { d = od; i = oi; }
}
__device__ __forceinline__ void sort64(float& d, int& i, bool asc, int lane) {
#pragma unroll
    for (int k = 2; k <= 64; k <<= 1) {
        bool ba = (((lane & k) == 0) == asc);
#pragma unroll
        for (int j = k >> 1; j > 0; j >>= 1) cswap(d, i, j, ba, lane);
    }
}
// sort m valid slots, keep lowest-64 lex-sorted in [0,64); return 32nd-smallest
__device__ __forceinline__ float wave_compact2(float* bd, int* bi, int m, int lane) {
    float d0 = (lane < m) ? bd[lane] : INFINITY;
    int   i0 = (lane < m) ? bi[lane] : 0x7fffffff;
    float d1 = (lane + 64 < m) ? bd[lane + 64] : INFINITY;
    int   i1 = (lane + 64 < m) ? bi[lane + 64] : 0x7fffffff;
    sort64(d0, i0, true, lane);
    sort64(d1, i1, false, lane);
    bool t = lessp(d1, i1, d0, i0);
    float ld = t ? d1 : d0;
    int   li = t ? i1 : i0;
#pragma unroll
    for (int j = 32; j > 0; j >>= 1) cswap(ld, li, j, true, lane);
    bd[lane] = ld; bi[lane] = li;
    return uni(__shfl(ld, 31));            // uniform across wave
}

__global__ __launch_bounds__(256, 4) void topk_kernel(const float* __restrict__ x,
                                                      const float* __restrict__ x_sq,
                                                      const float* __restrict__ sampled,
                                                      const float* __restrict__ s_sq,
                                                      int* __restrict__ nbr) {
    int b = blockIdx.x & 7;                 // XCD-by-batch swizzle
    int qg = blockIdx.x >> 3;               // 0..255
    int tid = threadIdx.x, lane = tid & 63;
    int w = __builtin_amdgcn_readfirstlane(tid >> 6);
    __shared__ float xs[64][36];
    __shared__ float bufd[8][128];
    __shared__ int   bufi[8][128];
    int s0 = qg * 8;                        // 8 queries per block, 2 per wave
    const float* xb = x + (size_t)b * (NN * FF);
    const float* xqb = x_sq + (size_t)b * NN;

    // 2 query feature vectors -> SGPRs via readfirstlane (wave-uniform)
    float sa0[32], sa1[32];
    {
        const float* sp0 = sampled + ((size_t)b * SS + s0 + w * 2 + 0) * FF;
        const float* sp1 = sampled + ((size_t)b * SS + s0 + w * 2 + 1) * FF;
#pragma unroll
        for (int k = 0; k < 32; k++) {
            sa0[k] = uni(sp0[k]);
            sa1[k] = uni(sp1[k]);
        }
    }
    float ssq0 = uni(s_sq[b * SS + s0 + w * 2 + 0]);
    float ssq1 = uni(s_sq[b * SS + s0 + w * 2 + 1]);

    float* bq0d = &bufd[w * 2 + 0][0];  int* bq0i = &bufi[w * 2 + 0][0];
    float* bq1d = &bufd[w * 2 + 1][0];  int* bq1i = &bufi[w * 2 + 1][0];
    int   cnt0 = 0, cnt1 = 0;              // wave-uniform (ballot popcounts)
    float tau0 = INFINITY, tau1 = INFINITY;

    for (int t = 0; t < NN / 64; t++) {
        int n0 = t * 64;
        __syncthreads();
        for (int i = tid; i < 512; i += 256) {
            int row = i >> 3, seg = i & 7;
            *(float4*)&xs[row][seg * 4] = *(const float4*)(xb + (size_t)(n0 + row) * FF + (seg << 2));
        }
        __syncthreads();

        int n = n0 + lane;
        float xq = xqb[n];                  // coalesced, L2-hot
        // both dot chains interleaved; ref-exact sequential FMA order each.
        float c0 = 0.f, c1 = 0.f;
        {
            const float4* rr = (const float4*)&xs[lane][0];
#pragma unroll
            for (int j = 0; j < 8; j++) {
                float4 v = rr[j];
                c0 = fmaf(sa0[4 * j], v.x, c0);     c1 = fmaf(sa1[4 * j], v.x, c1);
                c0 = fmaf(sa0[4 * j + 1], v.y, c0); c1 = fmaf(sa1[4 * j + 1], v.y, c1);
                c0 = fmaf(sa0[4 * j + 2], v.z, c0); c1 = fmaf(sa1[4 * j + 2], v.z, c1);
                c0 = fmaf(sa0[4 * j + 3], v.w, c0); c1 = fmaf(sa1[4 * j + 3], v.w, c1);
            }
        }
        float d0v = (ssq0 + xq) - (c0 + c0);   // ref combine order
        float d1v = (ssq1 + xq) - (c1 + c1);

        unsigned long long m0 = __ballot(d0v < tau0);
        if (m0) {
            int pos = cnt0 + __builtin_popcountll(m0 & ((1ull << lane) - 1ull));
            if (d0v < tau0) { bq0d[pos] = d0v; bq0i[pos] = n; }
            cnt0 += __builtin_popcountll(m0);
            if (cnt0 > 64) { tau0 = wave_compact2(bq0d, bq0i, cnt0, lane); cnt0 = 32; }
        }
        unsigned long long m1 = __ballot(d1v < tau1);
        if (m1) {
            int pos = cnt1 + __builtin_popcountll(m1 & ((1ull << lane) - 1ull));
            if (d1v < tau1) { bq1d[pos] = d1v; bq1i[pos] = n; }
            cnt1 += __builtin_popcountll(m1);
            if (cnt1 > 64) { tau1 = wave_compact2(bq1d, bq1i, cnt1, lane); cnt1 = 32; }
        }
    }
    // final: compact (lex-sorts survivors) and emit first 32 per query
    wave_compact2(bq0d, bq0i, cnt0, lane);
    wave_compact2(bq1d, bq1i, cnt1, lane);
    int s = s0 + w * 2;
    if (lane < 32) {
        nbr[((size_t)b * SS + s) * KK + lane] = bq0i[lane];
        nbr[((size_t)b * SS + s + 1) * KK + lane] = bq1i[lane];
    }
}

// ---------------------------------------------------------------------------
// K4: features_batch[b,o,s] = max_k h2[b, nbr[b,s,k], o]; block=128, 16 s/block
__global__ __launch_bounds__(128) void maxgather_kernel(const float* __restrict__ h2,
                                                        const int* __restrict__ nbr,
                                                        float* __restrict__ out_feat) {
    __shared__ float fs[128][17];
    int b = blockIdx.x & 7;
    int sg = blockIdx.x >> 3;               // 0..127
    int s0 = sg * 16;
    int tid = threadIdx.x;                  // o = tid (0..127)
    for (int si = 0; si < 16; si++) {
        int s = s0 + si;
        const int* row = nbr + ((size_t)b * SS + s) * KK;
        float m = -INFINITY;
#pragma unroll 4
        for (int k = 0; k < KK; k++) {
            int idx = row[k];
            float v = h2[((size_t)b * NN + idx) * OUTC + tid];
            m = fmaxf(m, v);
        }
        fs[tid][si] = m;
    }
    __syncthreads();
#pragma unroll
    for (int j = 0; j < 16; j++) {
        int flat = j * 128 + tid;
        int fo = flat >> 4, sw = flat & 15;
        out_feat[((size_t)b * OUTC + fo) * SS + s0 + sw] = fs[fo][sw];
    }
}

// ---------------------------------------------------------------------------
extern "C" void kernel_launch(void* const* d_in, const int* in_sizes, int n_in,
                              void* d_out, int out_size, void* d_ws, size_t ws_size,
                              hipStream_t stream) {
    const float* x    = (const float*)d_in[0];
    const int*   sidx = (const int*)d_in[1];
    const float* W1   = (const float*)d_in[2];
    const float* b1   = (const float*)d_in[3];
    const float* W2   = (const float*)d_in[4];
    const float* b2   = (const float*)d_in[5];

    float* out_feat = (float*)d_out;                       // [B,128,S]
    float* out_samp = out_feat + (size_t)BB * OUTC * SS;   // [B,32,S]

    float* h2      = (float*)d_ws;                         // B*N*128 fp32 = 64 MB
    float* sampled = h2 + (size_t)BB * NN * OUTC;          // B*S*F
    float* xsq     = sampled + (size_t)BB * SS * FF;       // B*N
    float* ssq     = xsq + (size_t)BB * NN;                // B*S
    int*   nbr     = (int*)(ssq + (size_t)BB * SS);        // B*S*K

    xsq_kernel<<<dim3(BB * NN / 256), dim3(256), 0, stream>>>(x, xsq);
    gather_kernel<<<dim3(BB * SS / 256), dim3(256), 0, stream>>>(x, sidx, sampled, ssq);
    mlp_kernel<<<dim3(BB * NN / 64), dim3(256), 0, stream>>>(x, W1, b1, W2, b2, h2);
    transpose_kernel<<<dim3(BB * SS / 64), dim3(256), 0, stream>>>(sampled, out_samp);
    topk_kernel<<<dim3(BB * SS / 8), dim3(256), 0, stream>>>(x, xsq, sampled, ssq, nbr);
    maxgather_kernel<<<dim3(BB * SS / 16), dim3(128), 0, stream>>>(h2, nbr, out_feat);
}

// Round 10
// 1090.635 us; speedup vs baseline: 1.5024x; 1.0354x over previous
//
#include <hip/hip_runtime.h>
#include <math.h>

#pragma clang fp contract(off)   // no implicit fusion; FMA only where ref has it

// Problem constants (fixed by the reference)
#define BB   8
#define NN   16384
#define FF   32
#define SS   2048
#define KK   32
#define OUTC 128

// force a value into uniform (SGPR) representation
__device__ __forceinline__ float uni(float v) {
    return __uint_as_float(__builtin_amdgcn_readfirstlane(__float_as_uint(v)));
}

// ---------------------------------------------------------------------------
// Reference-bit-exact fp32 helpers (validated R0-R7):
// x_sq / s_sq: numpy pairwise_sum scalar 8-accumulator block (n=32, no FMA)
__device__ __forceinline__ float np_sumsq32(const float* a) {
    float r[8];
#pragma unroll
    for (int j = 0; j < 8; j++) r[j] = a[j] * a[j];
#pragma unroll
    for (int t = 1; t < 4; t++) {
#pragma unroll
        for (int j = 0; j < 8; j++) {
            float e = a[8 * t + j] * a[8 * t + j];
            r[j] = r[j] + e;
        }
    }
    return ((r[0] + r[1]) + (r[2] + r[3])) + ((r[4] + r[5]) + (r[6] + r[7]));
}

// ---------------------------------------------------------------------------
// K1a: x_sq[b,n] = ref-order sum_f x^2
__global__ __launch_bounds__(256) void xsq_kernel(const float* __restrict__ x,
                                                  float* __restrict__ xsq) {
    int gid = blockIdx.x * 256 + threadIdx.x;      // < B*N
    const float4* r = (const float4*)(x + (size_t)gid * FF);
    float a[32];
#pragma unroll
    for (int j = 0; j < 8; j++) {
        float4 v = r[j];
        a[4 * j] = v.x; a[4 * j + 1] = v.y; a[4 * j + 2] = v.z; a[4 * j + 3] = v.w;
    }
    xsq[gid] = np_sumsq32(a);
}

// ---------------------------------------------------------------------------
// K1b: gather sampled features (row-major [B,S,F]) + ref-order s_sq
__global__ __launch_bounds__(256) void gather_kernel(const float* __restrict__ x,
                                                     const int* __restrict__ sidx,
                                                     float* __restrict__ sampled,
                                                     float* __restrict__ ssq) {
    int gid = blockIdx.x * 256 + threadIdx.x;      // < B*S
    int b = gid >> 11;
    int idx = sidx[gid];
    const float4* r = (const float4*)(x + ((size_t)b * NN + idx) * FF);
    float4* wo = (float4*)(sampled + (size_t)gid * FF);
    float a[32];
#pragma unroll
    for (int j = 0; j < 8; j++) {
        float4 v = r[j];
        a[4 * j] = v.x; a[4 * j + 1] = v.y; a[4 * j + 2] = v.z; a[4 * j + 3] = v.w;
        wo[j] = v;
    }
    ssq[gid] = np_sumsq32(a);
}

// ---------------------------------------------------------------------------
// K1c: sampled [B,S,F] -> output sampled_batch [B,F,S] (transpose via LDS)
__global__ __launch_bounds__(256) void transpose_kernel(const float* __restrict__ sampled,
                                                        float* __restrict__ out_samp) {
    __shared__ float tile[32][65];
    int b = blockIdx.x >> 5, sg = blockIdx.x & 31;
    int s0 = sg * 64;
    int tid = threadIdx.x;
    int f = tid & 31, si = tid >> 5;               // si in 0..7
#pragma unroll
    for (int r = 0; r < 8; r++) {
        int s = r * 8 + si;
        tile[f][s] = sampled[((size_t)b * SS + s0 + s) * FF + f];
    }
    __syncthreads();
#pragma unroll
    for (int r = 0; r < 8; r++) {
        int flat = r * 256 + tid;
        int fo = flat >> 6, sw = flat & 63;
        out_samp[((size_t)b * FF + fo) * SS + s0 + sw] = tile[fo][sw];
    }
}

// ---------------------------------------------------------------------------
// K2: per-point MLP, h2[b,n,:] = W2 @ relu(W1 @ x + b1) + b2  (fp32, VALU)
__global__ __launch_bounds__(256) void mlp_kernel(const float* __restrict__ x,
                                                  const float* __restrict__ W1,
                                                  const float* __restrict__ b1,
                                                  const float* __restrict__ W2,
                                                  const float* __restrict__ b2,
                                                  float* __restrict__ h2) {
    __shared__ float xs[64][36];          // padded
    __shared__ float hs[8512];            // h1t [128][65] then reused as h2s [64][133]
    int tid = threadIdx.x, lane = tid & 63;
    int wu = __builtin_amdgcn_readfirstlane(tid >> 6);
    size_t p0 = (size_t)blockIdx.x * 64;

    for (int i = tid; i < 64 * 8; i += 256) {
        int row = i >> 3, seg = i & 7;
        *(float4*)&xs[row][seg * 4] = *(const float4*)(x + (p0 + row) * FF + seg * 4);
    }
    __syncthreads();

    float xr[32];
    {
        const float4* r = (const float4*)&xs[lane][0];
#pragma unroll
        for (int j = 0; j < 8; j++) {
            float4 v = r[j];
            xr[4 * j] = v.x; xr[4 * j + 1] = v.y; xr[4 * j + 2] = v.z; xr[4 * j + 3] = v.w;
        }
    }
#pragma unroll 4
    for (int i = 0; i < 32; i++) {
        int o = wu * 32 + i;
        const float4* wr = (const float4*)(W1 + o * FF);
        float a = b1[o];
#pragma unroll
        for (int j = 0; j < 8; j++) {
            float4 v = wr[j];
            a = fmaf(v.x, xr[4 * j], a);     a = fmaf(v.y, xr[4 * j + 1], a);
            a = fmaf(v.z, xr[4 * j + 2], a); a = fmaf(v.w, xr[4 * j + 3], a);
        }
        hs[o * 65 + lane] = fmaxf(a, 0.f);
    }
    __syncthreads();
    float acc[32];
#pragma unroll
    for (int i = 0; i < 32; i++) acc[i] = b2[wu * 32 + i];
    for (int k4 = 0; k4 < 32; k4++) {
        float h0 = hs[(4 * k4 + 0) * 65 + lane];
        float h1v = hs[(4 * k4 + 1) * 65 + lane];
        float h2v = hs[(4 * k4 + 2) * 65 + lane];
        float h3v = hs[(4 * k4 + 3) * 65 + lane];
#pragma unroll
        for (int i = 0; i < 32; i++) {
            const float4 v = *(const float4*)(W2 + (wu * 32 + i) * OUTC + 4 * k4);
            acc[i] = fmaf(v.x, h0, acc[i]);  acc[i] = fmaf(v.y, h1v, acc[i]);
            acc[i] = fmaf(v.z, h2v, acc[i]); acc[i] = fmaf(v.w, h3v, acc[i]);
        }
    }
    __syncthreads();
#pragma unroll 4
    for (int i = 0; i < 32; i++) hs[lane * 133 + wu * 32 + i] = acc[i];
    __syncthreads();
    for (int j = 0; j < 32; j++) {
        int flat = j * 256 + tid;
        int p = flat >> 7, o = flat & 127;
        h2[(p0 + p) * OUTC + o] = hs[p * 133 + o];
    }
}

// ---------------------------------------------------------------------------
// K3 v4: SGPR queries (R9) + double-buffered LDS with register prefetch and
// ONE barrier per tile (R9 had load->barrier->compute->barrier: ~50% idle).
__device__ __forceinline__ bool lessp(float da, int ia, float db, int ib) {
    return da < db || (da == db && ia < ib);
}
__device__ __forceinline__ void cswap(float& d, int& i, int j, bool dirAsc, int lane) {
    float od = __shfl_xor(d, j);
    int   oi = __shfl_xor(i, j);
    bool lower = (lane & j) == 0;
    bool oLess = lessp(od, oi, d, i);
    if (oLess == (lower == dirAsc)) { d = od; i = oi; }
}
__device__ __forceinline__ void sort64(float& d, int& i, bool asc, int lane) {
#pragma unroll
    for (int k = 2; k <= 64; k <<= 1) {
        bool ba = (((lane & k) == 0) == asc);
#pragma unroll
        for (int j = k >> 1; j > 0; j >>= 1) cswap(d, i, j, ba, lane);
    }
}
// sort m valid slots, keep lowest-64 lex-sorted in [0,64); return 32nd-smallest
__device__ __forceinline__ float wave_compact2(float* bd, int* bi, int m, int lane) {
    float d0 = (lane < m) ? bd[lane] : INFINITY;
    int   i0 = (lane < m) ? bi[lane] : 0x7fffffff;
    float d1 = (lane + 64 < m) ? bd[lane + 64] : INFINITY;
    int   i1 = (lane + 64 < m) ? bi[lane + 64] : 0x7fffffff;
    sort64(d0, i0, true, lane);
    sort64(d1, i1, false, lane);
    bool t = lessp(d1, i1, d0, i0);
    float ld = t ? d1 : d0;
    int   li = t ? i1 : i0;
#pragma unroll
    for (int j = 32; j > 0; j >>= 1) cswap(ld, li, j, true, lane);
    bd[lane] = ld; bi[lane] = li;
    return uni(__shfl(ld, 31));            // uniform across wave
}

__global__ __launch_bounds__(256, 4) void topk_kernel(const float* __restrict__ x,
                                                      const float* __restrict__ x_sq,
                                                      const float* __restrict__ sampled,
                                                      const float* __restrict__ s_sq,
                                                      int* __restrict__ nbr) {
    int b = blockIdx.x & 7;                 // XCD-by-batch swizzle
    int qg = blockIdx.x >> 3;               // 0..255
    int tid = threadIdx.x, lane = tid & 63;
    int w = __builtin_amdgcn_readfirstlane(tid >> 6);
    __shared__ float xs[2][64][36];         // double buffer, padded rows
    __shared__ float bufd[8][128];
    __shared__ int   bufi[8][128];
    int s0 = qg * 8;                        // 8 queries per block, 2 per wave
    const float* xb = x + (size_t)b * (NN * FF);
    const float* xqb = x_sq + (size_t)b * NN;

    // 2 query feature vectors -> SGPRs via readfirstlane (wave-uniform)
    float sa0[32], sa1[32];
    {
        const float* sp0 = sampled + ((size_t)b * SS + s0 + w * 2 + 0) * FF;
        const float* sp1 = sampled + ((size_t)b * SS + s0 + w * 2 + 1) * FF;
#pragma unroll
        for (int k = 0; k < 32; k++) {
            sa0[k] = uni(sp0[k]);
            sa1[k] = uni(sp1[k]);
        }
    }
    float ssq0 = uni(s_sq[b * SS + s0 + w * 2 + 0]);
    float ssq1 = uni(s_sq[b * SS + s0 + w * 2 + 1]);

    float* bq0d = &bufd[w * 2 + 0][0];  int* bq0i = &bufi[w * 2 + 0][0];
    float* bq1d = &bufd[w * 2 + 1][0];  int* bq1i = &bufi[w * 2 + 1][0];
    int   cnt0 = 0, cnt1 = 0;              // wave-uniform (ballot popcounts)
    float tau0 = INFINITY, tau1 = INFINITY;

    // staging geometry: thread stages rows r0 and r0+32, 16B chunk c0
    int r0 = tid >> 3, c0 = (tid & 7) * 4;
    const float4* g0 = (const float4*)(xb + (size_t)r0 * FF + c0);
    const float4* g1 = (const float4*)(xb + (size_t)(r0 + 32) * FF + c0);
    // preamble: tile 0 -> regs -> xs[0]; prefetch tile 1 -> regs; xq tile 0
    float4 p0 = g0[0], p1 = g1[0];
    *(float4*)&xs[0][r0][c0] = p0;
    *(float4*)&xs[0][r0 + 32][c0] = p1;
    p0 = g0[512]; p1 = g1[512];             // tile 1 (512 float4 = 64 rows)
    float xq = xqb[lane];                   // x_sq for tile 0
    __syncthreads();

    for (int t = 0; t < NN / 64; t++) {
        int cur = t & 1;
        // stage tile t+1 (regs -> other buffer); concurrent with compute of t
        if (t + 1 < NN / 64) {
            *(float4*)&xs[1 - cur][r0][c0] = p0;
            *(float4*)&xs[1 - cur][r0 + 32][c0] = p1;
        }
        int n = t * 64 + lane;
        float xq_c = xq;
        // both dot chains interleaved; ref-exact sequential FMA order each.
        float c0a = 0.f, c1a = 0.f;
        {
            const float4* rr = (const float4*)&xs[cur][lane][0];
#pragma unroll
            for (int j = 0; j < 8; j++) {
                float4 v = rr[j];
                c0a = fmaf(sa0[4 * j], v.x, c0a);     c1a = fmaf(sa1[4 * j], v.x, c1a);
                c0a = fmaf(sa0[4 * j + 1], v.y, c0a); c1a = fmaf(sa1[4 * j + 1], v.y, c1a);
                c0a = fmaf(sa0[4 * j + 2], v.z, c0a); c1a = fmaf(sa1[4 * j + 2], v.z, c1a);
                c0a = fmaf(sa0[4 * j + 3], v.w, c0a); c1a = fmaf(sa1[4 * j + 3], v.w, c1a);
            }
        }
        // prefetch tile t+2 + next xq (long load->use distance: next iteration)
        if (t + 2 < NN / 64) {
            p0 = g0[(size_t)(t + 2) * 512];
            p1 = g1[(size_t)(t + 2) * 512];
        }
        if (t + 1 < NN / 64) xq = xqb[(t + 1) * 64 + lane];

        float d0v = (ssq0 + xq_c) - (c0a + c0a);   // ref combine order
        float d1v = (ssq1 + xq_c) - (c1a + c1a);

        unsigned long long m0 = __ballot(d0v < tau0);
        if (m0) {
            int pos = cnt0 + __builtin_popcountll(m0 & ((1ull << lane) - 1ull));
            if (d0v < tau0) { bq0d[pos] = d0v; bq0i[pos] = n; }
            cnt0 += __builtin_popcountll(m0);
            if (cnt0 > 64) { tau0 = wave_compact2(bq0d, bq0i, cnt0, lane); cnt0 = 32; }
        }
        unsigned long long m1 = __ballot(d1v < tau1);
        if (m1) {
            int pos = cnt1 + __builtin_popcountll(m1 & ((1ull << lane) - 1ull));
            if (d1v < tau1) { bq1d[pos] = d1v; bq1i[pos] = n; }
            cnt1 += __builtin_popcountll(m1);
            if (cnt1 > 64) { tau1 = wave_compact2(bq1d, bq1i, cnt1, lane); cnt1 = 32; }
        }
        __syncthreads();   // tile t reads done; tile t+1 writes visible
    }
    // final: compact (lex-sorts survivors) and emit first 32 per query
    wave_compact2(bq0d, bq0i, cnt0, lane);
    wave_compact2(bq1d, bq1i, cnt1, lane);
    int s = s0 + w * 2;
    if (lane < 32) {
        nbr[((size_t)b * SS + s) * KK + lane] = bq0i[lane];
        nbr[((size_t)b * SS + s + 1) * KK + lane] = bq1i[lane];
    }
}

// ---------------------------------------------------------------------------
// K4: features_batch[b,o,s] = max_k h2[b, nbr[b,s,k], o]; block=128, 16 s/block
__global__ __launch_bounds__(128) void maxgather_kernel(const float* __restrict__ h2,
                                                        const int* __restrict__ nbr,
                                                        float* __restrict__ out_feat) {
    __shared__ float fs[128][17];
    int b = blockIdx.x & 7;
    int sg = blockIdx.x >> 3;               // 0..127
    int s0 = sg * 16;
    int tid = threadIdx.x;                  // o = tid (0..127)
    for (int si = 0; si < 16; si++) {
        int s = s0 + si;
        const int* row = nbr + ((size_t)b * SS + s) * KK;
        float m = -INFINITY;
#pragma unroll 4
        for (int k = 0; k < KK; k++) {
            int idx = row[k];
            float v = h2[((size_t)b * NN + idx) * OUTC + tid];
            m = fmaxf(m, v);
        }
        fs[tid][si] = m;
    }
    __syncthreads();
#pragma unroll
    for (int j = 0; j < 16; j++) {
        int flat = j * 128 + tid;
        int fo = flat >> 4, sw = flat & 15;
        out_feat[((size_t)b * OUTC + fo) * SS + s0 + sw] = fs[fo][sw];
    }
}

// ---------------------------------------------------------------------------
extern "C" void kernel_launch(void* const* d_in, const int* in_sizes, int n_in,
                              void* d_out, int out_size, void* d_ws, size_t ws_size,
                              hipStream_t stream) {
    const float* x    = (const float*)d_in[0];
    const int*   sidx = (const int*)d_in[1];
    const float* W1   = (const float*)d_in[2];
    const float* b1   = (const float*)d_in[3];
    const float* W2   = (const float*)d_in[4];
    const float* b2   = (const float*)d_in[5];

    float* out_feat = (float*)d_out;                       // [B,128,S]
    float* out_samp = out_feat + (size_t)BB * OUTC * SS;   // [B,32,S]

    float* h2      = (float*)d_ws;                         // B*N*128 fp32 = 64 MB
    float* sampled = h2 + (size_t)BB * NN * OUTC;          // B*S*F
    float* xsq     = sampled + (size_t)BB * SS * FF;       // B*N
    float* ssq     = xsq + (size_t)BB * NN;                // B*S
    int*   nbr     = (int*)(ssq + (size_t)BB * SS);        // B*S*K

    xsq_kernel<<<dim3(BB * NN / 256), dim3(256), 0, stream>>>(x, xsq);
    gather_kernel<<<dim3(BB * SS / 256), dim3(256), 0, stream>>>(x, sidx, sampled, ssq);
    mlp_kernel<<<dim3(BB * NN / 64), dim3(256), 0, stream>>>(x, W1, b1, W2, b2, h2);
    transpose_kernel<<<dim3(BB * SS / 64), dim3(256), 0, stream>>>(sampled, out_samp);
    topk_kernel<<<dim3(BB * SS / 8), dim3(256), 0, stream>>>(x, xsq, sampled, ssq, nbr);
    maxgather_kernel<<<dim3(BB * SS / 16), dim3(128), 0, stream>>>(h2, nbr, out_feat);
}